// Round 7
// baseline (16475.409 us; speedup 1.0000x reference)
//
#include <hip/hip_runtime.h>

// Exact serial RK4 scan — hand-scheduled packed-f32 asm + DVFS spinners.
// R1: parallel-in-time impossible (positive conditional Lyapunov exponent).
// R3: 180 cy/step @1 wave = in-order dep stalls from back-to-back dependent
// VOP3P ops. This round: same 30 packed ops per step (bit-identical math),
// reordered so dependent pairs are separated by >=1 independent issue
// (gap-1 = 4cy covers dep latency); stores moved into the asm block with
// offset immediates. Spinners unchanged from R3 (+26% proven).
// (R6 resubmission of R4 — two GPU-acquisition timeouts in a row.)

typedef float v2f __attribute__((ext_vector_type(2)));
typedef float v4f __attribute__((ext_vector_type(4)));

__device__ unsigned int g_done_ctr = 0;

// One RK4 step, hand-scheduled. Stores this step's result (P',V') to
// [optr+OFS0], [optr+OFS1]. Uses names CA,CB,CC,H2v,Hv,H6v,TWOv,optr from
// the enclosing scope. Arithmetic identical to R2/R3 (absmax-preserving).
#define RK4_STEP_SCHED(CDv, OFS0, OFS1)                                      \
{                                                                            \
    v2f mA, mB, cA, cB, dA, dB, f1, f2, f3, f4;                              \
    v2f yP, yV, zP, zV, wP, wV, t, s;                                        \
    asm volatile(                                                            \
        "v_pk_mul_f32 %[mA], %[P], %[P] op_sel:[1,1] op_sel_hi:[0,1]\n\t"    \
        "v_pk_fma_f32 %[yP], %[H2], %[V], %[P]\n\t"                          \
        "v_pk_fma_f32 %[cA], %[CC], %[mA], %[CD]\n\t"                        \
        "v_pk_mul_f32 %[mB], %[yP], %[yP] op_sel:[1,1] op_sel_hi:[0,1]\n\t"  \
        "v_pk_fma_f32 %[dA], %[CB], %[P], %[cA]\n\t"                         \
        "v_pk_fma_f32 %[cB], %[CC], %[mB], %[CD]\n\t"                        \
        "v_pk_fma_f32 %[f1], %[CA], %[V], %[dA]\n\t"                         \
        "v_pk_fma_f32 %[dB], %[CB], %[yP], %[cB]\n\t"                        \
        "v_pk_fma_f32 %[yV], %[H2], %[f1], %[V]\n\t"                         \
        "v_pk_fma_f32 %[f2], %[CA], %[yV], %[dB]\n\t"                        \
        "v_pk_fma_f32 %[zP], %[H2], %[yV], %[P]\n\t"                         \
        "v_pk_fma_f32 %[t],  %[TWO], %[yV], %[V]\n\t"                        \
        "v_pk_fma_f32 %[zV], %[H2], %[f2], %[V]\n\t"                         \
        "v_pk_mul_f32 %[mA], %[zP], %[zP] op_sel:[1,1] op_sel_hi:[0,1]\n\t"  \
        "v_pk_fma_f32 %[s],  %[TWO], %[f2], %[f1]\n\t"                       \
        "v_pk_fma_f32 %[cA], %[CC], %[mA], %[CD]\n\t"                        \
        "v_pk_fma_f32 %[wP], %[H],  %[zV], %[P]\n\t"                         \
        "v_pk_fma_f32 %[t],  %[TWO], %[zV], %[t]\n\t"                        \
        "v_pk_fma_f32 %[dA], %[CB], %[zP], %[cA]\n\t"                        \
        "v_pk_mul_f32 %[mB], %[wP], %[wP] op_sel:[1,1] op_sel_hi:[0,1]\n\t"  \
        "v_pk_fma_f32 %[f3], %[CA], %[zV], %[dA]\n\t"                        \
        "v_pk_fma_f32 %[cB], %[CC], %[mB], %[CD]\n\t"                        \
        "v_pk_fma_f32 %[wV], %[H],  %[f3], %[V]\n\t"                         \
        "v_pk_fma_f32 %[dB], %[CB], %[wP], %[cB]\n\t"                        \
        "v_pk_fma_f32 %[s],  %[TWO], %[f3], %[s]\n\t"                        \
        "v_pk_add_f32 %[t],  %[t], %[wV]\n\t"                                \
        "v_pk_fma_f32 %[f4], %[CA], %[wV], %[dB]\n\t"                        \
        "v_pk_fma_f32 %[P],  %[H6], %[t], %[P]\n\t"                          \
        "v_pk_add_f32 %[s],  %[s], %[f4]\n\t"                                \
        "global_store_dwordx2 %[ptr], %[P], off offset:" #OFS0 "\n\t"        \
        "v_pk_fma_f32 %[V],  %[H6], %[s], %[V]\n\t"                          \
        "global_store_dwordx2 %[ptr], %[V], off offset:" #OFS1 "\n\t"        \
        : [P]"+v"(P), [V]"+v"(V),                                            \
          [mA]"=&v"(mA), [mB]"=&v"(mB), [cA]"=&v"(cA), [cB]"=&v"(cB),        \
          [dA]"=&v"(dA), [dB]"=&v"(dB),                                      \
          [f1]"=&v"(f1), [f2]"=&v"(f2), [f3]"=&v"(f3), [f4]"=&v"(f4),        \
          [yP]"=&v"(yP), [yV]"=&v"(yV), [zP]"=&v"(zP), [zV]"=&v"(zV),        \
          [wP]"=&v"(wP), [wV]"=&v"(wV), [t]"=&v"(t), [s]"=&v"(s)             \
        : [CD]"v"(CDv), [CA]"v"(CA), [CB]"v"(CB), [CC]"v"(CC),               \
          [H2]"v"(H2v), [H]"v"(Hv), [H6]"v"(H6v), [TWO]"v"(TWOv),            \
          [ptr]"v"(optr)                                                     \
        : "memory");                                                         \
}

__global__ void __launch_bounds__(256, 1)
rk4_scan_sched_kernel(const float* __restrict__ u,
                      const float* __restrict__ pk1, const float* __restrict__ pk2,
                      const float* __restrict__ pk3, const float* __restrict__ pk4,
                      const float* __restrict__ pk5, const float* __restrict__ pk6,
                      float* __restrict__ out, int T)
{
    if (blockIdx.x != 0) {
        // ---- spinner (identical to R3): keep SCLK high until chain done ----
        const unsigned v0 = atomicAdd(&g_done_ctr, 0u);
        float a0 = (float)threadIdx.x + 1.0f, a1 = a0 + 0.5f, a2 = a0 + 1.5f,
              a3 = a0 + 2.5f, a4 = a0 + 3.5f, a5 = a0 + 4.5f, a6 = a0 + 5.5f,
              a7 = a0 + 6.5f;
        const float mu = 1.0000001f, ad = 0.4999999f;
        for (long it = 0; it < 20000000L; ++it) {
            a0 = __builtin_fmaf(a0, mu, ad); a1 = __builtin_fmaf(a1, mu, ad);
            a2 = __builtin_fmaf(a2, mu, ad); a3 = __builtin_fmaf(a3, mu, ad);
            a4 = __builtin_fmaf(a4, mu, ad); a5 = __builtin_fmaf(a5, mu, ad);
            a6 = __builtin_fmaf(a6, mu, ad); a7 = __builtin_fmaf(a7, mu, ad);
            if ((it & 1023) == 0) {
                if (atomicAdd(&g_done_ctr, 0u) != v0) break;
            }
        }
        asm volatile("" :: "v"(a0), "v"(a1), "v"(a2), "v"(a3),
                           "v"(a4), "v"(a5), "v"(a6), "v"(a7));
        return;
    }
    if (threadIdx.x != 0) return;

    const float k1 = *pk1, k2 = *pk2, k3 = *pk3;
    const float k4 = *pk4, k5 = *pk5, k6 = *pk6;

    const float c034 = 0.5f * k3 * k4;
    const float k36  = k3 * k6;
    const float k6u  = k6 * 1.0f;

    const v2f CA   = { k1,    k5   };
    const v2f CB   = { k2,    k36  };
    const v2f CC   = { c034, -k36  };
    const v2f H2v  = { 0.05f, 0.05f };
    const v2f Hv   = { 0.1f,  0.1f  };
    const v2f H6v  = { 0.1f / 6.0f, 0.1f / 6.0f };
    const v2f TWOv = { 2.0f,  2.0f };

    v2f P = { 0.f, 0.f };   // (x0, x1)
    v2f V = { 0.f, 0.f };   // (x2, x3)

    const int nc = T >> 3;
    const v4f* __restrict__ u4 = reinterpret_cast<const v4f*>(u);
    unsigned long long optr = (unsigned long long)out;   // byte address of out[t]

    if (nc > 0) {
        v4f A0 = u4[0], A1 = u4[1];
        v4f B0 = (nc > 1) ? u4[2] : A0;
        v4f B1 = (nc > 1) ? u4[3] : A1;

        for (int c = 0; c < nc; ++c) {
            const int p = (c + 2 < nc) ? (c + 2) : (nc - 1);
            v4f N0 = u4[2 * p];
            v4f N1 = u4[2 * p + 1];

            v2f cd0, cd1, cd2, cd3, cd4, cd5, cd6, cd7;
            cd0.x = k4 * A0.x; cd0.y = k6u;
            cd1.x = k4 * A0.y; cd1.y = k6u;
            cd2.x = k4 * A0.z; cd2.y = k6u;
            cd3.x = k4 * A0.w; cd3.y = k6u;
            cd4.x = k4 * A1.x; cd4.y = k6u;
            cd5.x = k4 * A1.y; cd5.y = k6u;
            cd6.x = k4 * A1.z; cd6.y = k6u;
            cd7.x = k4 * A1.w; cd7.y = k6u;

            RK4_STEP_SCHED(cd0,   0,   8)
            RK4_STEP_SCHED(cd1,  16,  24)
            RK4_STEP_SCHED(cd2,  32,  40)
            RK4_STEP_SCHED(cd3,  48,  56)
            RK4_STEP_SCHED(cd4,  64,  72)
            RK4_STEP_SCHED(cd5,  80,  88)
            RK4_STEP_SCHED(cd6,  96, 104)
            RK4_STEP_SCHED(cd7, 112, 120)

            optr += 128;
            A0 = B0; A1 = B1; B0 = N0; B1 = N1;
        }
    }
    // tail (T % 8 != 0; not hit for T=200000)
    for (int t = nc << 3; t < T; ++t) {
        v2f cd; cd.x = k4 * u[t]; cd.y = k6u;
        RK4_STEP_SCHED(cd, 0, 8)
        optr += 16;
    }

    __threadfence();
    atomicAdd(&g_done_ctr, 1u);
}

extern "C" void kernel_launch(void* const* d_in, const int* in_sizes, int n_in,
                              void* d_out, int out_size, void* d_ws, size_t ws_size,
                              hipStream_t stream)
{
    const float* u   = (const float*)d_in[0];
    const float* pk1 = (const float*)d_in[1];
    const float* pk2 = (const float*)d_in[2];
    const float* pk3 = (const float*)d_in[3];
    const float* pk4 = (const float*)d_in[4];
    const float* pk5 = (const float*)d_in[5];
    const float* pk6 = (const float*)d_in[6];
    float* out = (float*)d_out;
    const int T = in_sizes[0];

    hipLaunchKernelGGL(rk4_scan_sched_kernel, dim3(257), dim3(256), 0, stream,
                       u, pk1, pk2, pk3, pk4, pk5, pk6, out, T);
}

// Round 8
// 14786.861 us; speedup vs baseline: 1.1142x; 1.1142x over previous
//
#include <hip/hip_runtime.h>

// Exact serial RK4 scan. R1: parallel-in-time impossible (lambda>0).
// R7: hand-scheduling changed nothing -> issue-cadence-bound, ~5.3cy/VALU-op.
// R8 levers: (1) 256 blocks (not 257) so no spinner co-resides on the chain
// wave's CU; (2) CD=(k4*u[t],k6) precomputed by a parallel kernel into d_ws,
// chain loads it on the VMEM pipe (kills per-step muls + register shuffles);
// (3) 16-step x2 double-buffered unroll (renaming, no v_movs).
// Chain asm = R3's proven block, verbatim (bit-identical arithmetic).

typedef float v2f __attribute__((ext_vector_type(2)));
typedef float v4f __attribute__((ext_vector_type(4)));

__device__ unsigned int g_done_ctr = 0;

static __device__ __forceinline__ void rk4_step_pk(
    v2f& P, v2f& V, v2f CD, v2f CA, v2f CB, v2f CC,
    v2f H2v, v2f Hv, v2f H6v, v2f TWOv)
{
    v2f m, b, t, s, f1, f2, f3, f4, yP, yV, zP, zV, wP, wV;
    asm volatile(
        "v_pk_mul_f32 %[m], %[P], %[P] op_sel:[1,1] op_sel_hi:[0,1]\n\t"
        "v_pk_fma_f32 %[b], %[CC], %[m], %[CD]\n\t"
        "v_pk_fma_f32 %[b], %[CB], %[P], %[b]\n\t"
        "v_pk_fma_f32 %[f1], %[CA], %[V], %[b]\n\t"
        "v_pk_fma_f32 %[yP], %[H2], %[V], %[P]\n\t"
        "v_pk_fma_f32 %[yV], %[H2], %[f1], %[V]\n\t"
        "v_pk_mul_f32 %[m], %[yP], %[yP] op_sel:[1,1] op_sel_hi:[0,1]\n\t"
        "v_pk_fma_f32 %[b], %[CC], %[m], %[CD]\n\t"
        "v_pk_fma_f32 %[b], %[CB], %[yP], %[b]\n\t"
        "v_pk_fma_f32 %[f2], %[CA], %[yV], %[b]\n\t"
        "v_pk_fma_f32 %[zP], %[H2], %[yV], %[P]\n\t"
        "v_pk_fma_f32 %[zV], %[H2], %[f2], %[V]\n\t"
        "v_pk_mul_f32 %[m], %[zP], %[zP] op_sel:[1,1] op_sel_hi:[0,1]\n\t"
        "v_pk_fma_f32 %[b], %[CC], %[m], %[CD]\n\t"
        "v_pk_fma_f32 %[b], %[CB], %[zP], %[b]\n\t"
        "v_pk_fma_f32 %[f3], %[CA], %[zV], %[b]\n\t"
        "v_pk_fma_f32 %[wP], %[H], %[zV], %[P]\n\t"
        "v_pk_fma_f32 %[wV], %[H], %[f3], %[V]\n\t"
        "v_pk_mul_f32 %[m], %[wP], %[wP] op_sel:[1,1] op_sel_hi:[0,1]\n\t"
        "v_pk_fma_f32 %[b], %[CC], %[m], %[CD]\n\t"
        "v_pk_fma_f32 %[b], %[CB], %[wP], %[b]\n\t"
        "v_pk_fma_f32 %[f4], %[CA], %[wV], %[b]\n\t"
        "v_pk_fma_f32 %[t], %[TWO], %[yV], %[V]\n\t"
        "v_pk_fma_f32 %[t], %[TWO], %[zV], %[t]\n\t"
        "v_pk_add_f32 %[t], %[t], %[wV]\n\t"
        "v_pk_fma_f32 %[P], %[H6], %[t], %[P]\n\t"
        "v_pk_fma_f32 %[s], %[TWO], %[f2], %[f1]\n\t"
        "v_pk_fma_f32 %[s], %[TWO], %[f3], %[s]\n\t"
        "v_pk_add_f32 %[s], %[s], %[f4]\n\t"
        "v_pk_fma_f32 %[V], %[H6], %[s], %[V]\n\t"
        : [P]"+v"(P), [V]"+v"(V),
          [m]"=&v"(m), [b]"=&v"(b), [t]"=&v"(t), [s]"=&v"(s),
          [f1]"=&v"(f1), [f2]"=&v"(f2), [f3]"=&v"(f3), [f4]"=&v"(f4),
          [yP]"=&v"(yP), [yV]"=&v"(yV), [zP]"=&v"(zP), [zV]"=&v"(zV),
          [wP]"=&v"(wP), [wV]"=&v"(wV)
        : [CD]"v"(CD), [CA]"v"(CA), [CB]"v"(CB), [CC]"v"(CC),
          [H2]"v"(H2v), [H]"v"(Hv), [H6]"v"(H6v), [TWO]"v"(TWOv));
}

// CD precompute: cd[t] = (k4*u[t], k6*1.0f). Trivially parallel, ~10us.
__global__ void cd_precompute_kernel(const float* __restrict__ u,
                                     const float* __restrict__ pk4,
                                     const float* __restrict__ pk6,
                                     v2f* __restrict__ cd, int T)
{
    const int t = blockIdx.x * 256 + threadIdx.x;
    if (t < T) {
        v2f c;
        c.x = (*pk4) * u[t];      // same single f32 mul as the inline path
        c.y = (*pk6) * 1.0f;
        cd[t] = c;
    }
}

#define DECL_SET(p) v2f p##0,p##1,p##2,p##3,p##4,p##5,p##6,p##7, \
                        p##8,p##9,p##10,p##11,p##12,p##13,p##14,p##15;
#define LOAD_SET(p, base) \
    p##0=(base)[0];  p##1=(base)[1];  p##2=(base)[2];  p##3=(base)[3];   \
    p##4=(base)[4];  p##5=(base)[5];  p##6=(base)[6];  p##7=(base)[7];   \
    p##8=(base)[8];  p##9=(base)[9];  p##10=(base)[10]; p##11=(base)[11];\
    p##12=(base)[12]; p##13=(base)[13]; p##14=(base)[14]; p##15=(base)[15];
#define DO_STEP(CDv, J)                                               \
    rk4_step_pk(P, V, CDv, CA, CB, CC, H2v, Hv, H6v, TWOv);           \
    ob[2*(J)]   = P;                                                  \
    ob[2*(J)+1] = V;
#define STEPS_SET(p)                                                  \
    DO_STEP(p##0,0)  DO_STEP(p##1,1)  DO_STEP(p##2,2)  DO_STEP(p##3,3)\
    DO_STEP(p##4,4)  DO_STEP(p##5,5)  DO_STEP(p##6,6)  DO_STEP(p##7,7)\
    DO_STEP(p##8,8)  DO_STEP(p##9,9)  DO_STEP(p##10,10) DO_STEP(p##11,11)\
    DO_STEP(p##12,12) DO_STEP(p##13,13) DO_STEP(p##14,14) DO_STEP(p##15,15)

__global__ void __launch_bounds__(256, 1)
rk4_chain_kernel(const float* __restrict__ u, const v2f* __restrict__ cdp,
                 const float* __restrict__ pk1, const float* __restrict__ pk2,
                 const float* __restrict__ pk3, const float* __restrict__ pk4,
                 const float* __restrict__ pk5, const float* __restrict__ pk6,
                 v2f* __restrict__ out2, int T)
{
    if (blockIdx.x != 0) {
        // ---- spinner (R3-proven): keep SCLK boosted until chain done ----
        const unsigned v0 = atomicAdd(&g_done_ctr, 0u);
        float a0 = (float)threadIdx.x + 1.0f, a1 = a0 + 0.5f, a2 = a0 + 1.5f,
              a3 = a0 + 2.5f, a4 = a0 + 3.5f, a5 = a0 + 4.5f, a6 = a0 + 5.5f,
              a7 = a0 + 6.5f;
        const float mu = 1.0000001f, ad = 0.4999999f;
        for (long it = 0; it < 20000000L; ++it) {
            a0 = __builtin_fmaf(a0, mu, ad); a1 = __builtin_fmaf(a1, mu, ad);
            a2 = __builtin_fmaf(a2, mu, ad); a3 = __builtin_fmaf(a3, mu, ad);
            a4 = __builtin_fmaf(a4, mu, ad); a5 = __builtin_fmaf(a5, mu, ad);
            a6 = __builtin_fmaf(a6, mu, ad); a7 = __builtin_fmaf(a7, mu, ad);
            if ((it & 1023) == 0) {
                if (atomicAdd(&g_done_ctr, 0u) != v0) break;
            }
        }
        asm volatile("" :: "v"(a0), "v"(a1), "v"(a2), "v"(a3),
                           "v"(a4), "v"(a5), "v"(a6), "v"(a7));
        return;
    }
    if (threadIdx.x != 0) return;

    const float k1 = *pk1, k2 = *pk2, k3 = *pk3;
    const float k4 = *pk4, k5 = *pk5, k6 = *pk6;

    const float c034 = 0.5f * k3 * k4;
    const float k36  = k3 * k6;
    const float k6u  = k6 * 1.0f;

    const v2f CA   = { k1,    k5   };
    const v2f CB   = { k2,    k36  };
    const v2f CC   = { c034, -k36  };
    const v2f H2v  = { 0.05f, 0.05f };
    const v2f Hv   = { 0.1f,  0.1f  };
    const v2f H6v  = { 0.1f / 6.0f, 0.1f / 6.0f };
    const v2f TWOv = { 2.0f,  2.0f };

    v2f P = { 0.f, 0.f };   // (x0, x1)
    v2f V = { 0.f, 0.f };   // (x2, x3)

    v2f* ob = out2;
    const int nb = T >> 4;           // 16-step blocks
    int b = 0;

    if (cdp != nullptr) {
        // -------- fast path: CDs streamed from the precomputed buffer ------
        if (nb >= 1) {
            DECL_SET(A) DECL_SET(B)
            LOAD_SET(A, cdp)
            for (; b + 1 < nb; b += 2) {
                const v2f* nB = cdp + (size_t)(b + 1) * 16;
                LOAD_SET(B, nB)
                STEPS_SET(A)
                ob += 32;
                const v2f* nA = cdp + (size_t)((b + 2 < nb) ? b + 2 : nb - 1) * 16;
                LOAD_SET(A, nA)
                STEPS_SET(B)
                ob += 32;
            }
            if (b < nb) {            // odd nb: last block sits in A
                STEPS_SET(A)
                ob += 32;
                ++b;
            }
        }
    } else {
        // -------- fallback (tiny d_ws): compute CDs inline, R3-style ------
        for (; b < nb; ++b) {
            const float* ub = u + (size_t)b * 16;
            DECL_SET(A)
            A0.x=k4*ub[0];  A0.y=k6u;  A1.x=k4*ub[1];  A1.y=k6u;
            A2.x=k4*ub[2];  A2.y=k6u;  A3.x=k4*ub[3];  A3.y=k6u;
            A4.x=k4*ub[4];  A4.y=k6u;  A5.x=k4*ub[5];  A5.y=k6u;
            A6.x=k4*ub[6];  A6.y=k6u;  A7.x=k4*ub[7];  A7.y=k6u;
            A8.x=k4*ub[8];  A8.y=k6u;  A9.x=k4*ub[9];  A9.y=k6u;
            A10.x=k4*ub[10]; A10.y=k6u; A11.x=k4*ub[11]; A11.y=k6u;
            A12.x=k4*ub[12]; A12.y=k6u; A13.x=k4*ub[13]; A13.y=k6u;
            A14.x=k4*ub[14]; A14.y=k6u; A15.x=k4*ub[15]; A15.y=k6u;
            STEPS_SET(A)
            ob += 32;
        }
    }

    // scalar tail (T % 16 != 0; not hit for T=200000)
    for (int t = nb << 4; t < T; ++t) {
        v2f cdv; cdv.x = k4 * u[t]; cdv.y = k6u;
        rk4_step_pk(P, V, cdv, CA, CB, CC, H2v, Hv, H6v, TWOv);
        out2[2 * t]     = P;
        out2[2 * t + 1] = V;
    }

    __threadfence();
    atomicAdd(&g_done_ctr, 1u);
}

extern "C" void kernel_launch(void* const* d_in, const int* in_sizes, int n_in,
                              void* d_out, int out_size, void* d_ws, size_t ws_size,
                              hipStream_t stream)
{
    const float* u   = (const float*)d_in[0];
    const float* pk1 = (const float*)d_in[1];
    const float* pk2 = (const float*)d_in[2];
    const float* pk3 = (const float*)d_in[3];
    const float* pk4 = (const float*)d_in[4];
    const float* pk5 = (const float*)d_in[5];
    const float* pk6 = (const float*)d_in[6];
    v2f* out2 = (v2f*)d_out;
    const int T = in_sizes[0];

    v2f* cd = nullptr;
    if (ws_size >= (size_t)T * sizeof(v2f)) {
        cd = (v2f*)d_ws;
        const int pre_blocks = (T + 255) / 256;
        hipLaunchKernelGGL(cd_precompute_kernel, dim3(pre_blocks), dim3(256),
                           0, stream, u, pk4, pk6, cd, T);
    }

    // 256 blocks exactly: the chain block's CU hosts NO spinner (R8 lever 1).
    hipLaunchKernelGGL(rk4_chain_kernel, dim3(256), dim3(256), 0, stream,
                       u, cd, pk1, pk2, pk3, pk4, pk5, pk6, out2, T);
}

// Round 9
// 12509.805 us; speedup vs baseline: 1.3170x; 1.1820x over previous
//
#include <hip/hip_runtime.h>

// Exact serial RK4 scan — dependency-cycle-minimized packed-f32 asm.
// Evidence: R4 (reorder)=neutral, R8 (-4 issues)=neutral -> bound by the
// loop-carried dep CYCLE (~14 ops x ~12.5cy = 175cy/step measured).
// R9: exploit linearity of each RK4 stage in the previous f:
//   f2 = (CA*H2)of1 + E2,  E2 = CA oV + CB o yP + CC o yP^2sel + CD
//   zP = yP + H2^2*f1,     wP = (P+H*V) + (H*H2)*f2
//   f3 = (CA*H2)of2 + E3,  f4 = (CA*H)of3 + E4
//   P' = (P+H*V) + (H^2/6)(f1+f2+f3),  V' = V + H6 f1 + H3 f2 + H3 f3 + H6 f4
// -> critical circuit 9 ops (was 14), 28 packed ops total. Pure reassociation
// of the same real-valued map. a1=CB*P+CD and m1=P^2sel are software-pipelined
// (computed from P' at the end of the previous step).

typedef float v2f __attribute__((ext_vector_type(2)));
typedef float v4f __attribute__((ext_vector_type(4)));

__device__ unsigned int g_done_ctr = 0;

// One step. In/out: P,V,a1,m1. CDv = this step's (k4*Fs, k6u); CDNv = next's.
// Consts from enclosing scope: CAc,CBc,CCc,cH2,cHc,H2c,Hc,H2q,HH2,H6c,H3c,Hq6.
#define RK4_STEP(CDv, CDNv)                                                   \
{                                                                             \
    v2f r0, r1, r2, r3, r4, r5, r6, r7;                                       \
    asm volatile(                                                             \
        "v_pk_fma_f32 %[r0], %[H2c], %[V], %[P]\n\t"   /* yP          */      \
        "v_pk_fma_f32 %[r1], %[Hc],  %[V], %[P]\n\t"   /* A2 = P+H V  */      \
        "v_pk_fma_f32 %[r2], %[CAc], %[V], %[CD]\n\t"  /* e1          */      \
        "v_pk_fma_f32 %[r3], %[CAc], %[V], %[a1]\n\t"  /* a2          */      \
        "v_pk_mul_f32 %[r4], %[r0], %[r0] op_sel:[1,1] op_sel_hi:[0,1]\n\t"   \
        "v_pk_fma_f32 %[r5], %[CBc], %[r0], %[r2]\n\t" /* e2          */      \
        "v_pk_fma_f32 %[r6], %[CCc], %[m1], %[r3]\n\t" /* f1          */      \
        "v_pk_fma_f32 %[r5], %[CCc], %[r4], %[r5]\n\t" /* E2          */      \
        "v_pk_fma_f32 %[r3], %[H2q], %[r6], %[r0]\n\t" /* zP          */      \
        "v_pk_fma_f32 %[r0], %[H6c], %[r6], %[V]\n\t"  /* v1          */      \
        "v_pk_fma_f32 %[r4], %[Hq6], %[r6], %[r1]\n\t" /* p1          */      \
        "v_pk_fma_f32 %[r7], %[cH2], %[r6], %[r5]\n\t" /* f2          */      \
        "v_pk_mul_f32 %[r5], %[r3], %[r3] op_sel:[1,1] op_sel_hi:[0,1]\n\t"   \
        "v_pk_fma_f32 %[r6], %[CBc], %[r3], %[r2]\n\t" /* g2          */      \
        "v_pk_fma_f32 %[r3], %[HH2], %[r7], %[r1]\n\t" /* wP          */      \
        "v_pk_fma_f32 %[r1], %[H3c], %[r7], %[r0]\n\t" /* v2          */      \
        "v_pk_fma_f32 %[r0], %[Hq6], %[r7], %[r4]\n\t" /* p2          */      \
        "v_pk_fma_f32 %[r6], %[CCc], %[r5], %[r6]\n\t" /* E3          */      \
        "v_pk_mul_f32 %[r5], %[r3], %[r3] op_sel:[1,1] op_sel_hi:[0,1]\n\t"   \
        "v_pk_fma_f32 %[r4], %[CBc], %[r3], %[r2]\n\t" /* h2          */      \
        "v_pk_fma_f32 %[r2], %[cH2], %[r7], %[r6]\n\t" /* f3          */      \
        "v_pk_fma_f32 %[r4], %[CCc], %[r5], %[r4]\n\t" /* E4          */      \
        "v_pk_fma_f32 %[r1], %[H3c], %[r2], %[r1]\n\t" /* v3          */      \
        "v_pk_fma_f32 %[P],  %[Hq6], %[r2], %[r0]\n\t" /* P'          */      \
        "v_pk_fma_f32 %[r0], %[cHc], %[r2], %[r4]\n\t" /* f4          */      \
        "v_pk_mul_f32 %[m1], %[P], %[P] op_sel:[1,1] op_sel_hi:[0,1]\n\t"     \
        "v_pk_fma_f32 %[a1], %[CBc], %[P], %[CDN]\n\t" /* a1' next    */      \
        "v_pk_fma_f32 %[V],  %[H6c], %[r0], %[r1]\n\t" /* V'          */      \
        : [P]"+v"(P), [V]"+v"(V), [a1]"+v"(a1), [m1]"+v"(m1),                 \
          [r0]"=&v"(r0), [r1]"=&v"(r1), [r2]"=&v"(r2), [r3]"=&v"(r3),         \
          [r4]"=&v"(r4), [r5]"=&v"(r5), [r6]"=&v"(r6), [r7]"=&v"(r7)          \
        : [CD]"v"(CDv), [CDN]"v"(CDNv),                                       \
          [CAc]"v"(CAc), [CBc]"v"(CBc), [CCc]"v"(CCc),                        \
          [cH2]"v"(cH2), [cHc]"v"(cHc), [H2c]"v"(H2c), [Hc]"v"(Hc),           \
          [H2q]"v"(H2q), [HH2]"v"(HH2), [H6c]"v"(H6c), [H3c]"v"(H3c),         \
          [Hq6]"v"(Hq6));                                                     \
}

// CD precompute: cd[t] = (k4*u[t], k6*1.0f). Trivially parallel.
__global__ void cd_precompute_kernel(const float* __restrict__ u,
                                     const float* __restrict__ pk4,
                                     const float* __restrict__ pk6,
                                     v2f* __restrict__ cd, int T)
{
    const int t = blockIdx.x * 256 + threadIdx.x;
    if (t < T) {
        v2f c;
        c.x = (*pk4) * u[t];
        c.y = (*pk6) * 1.0f;
        cd[t] = c;
    }
}

#define DECL_SET(p) v2f p##0,p##1,p##2,p##3,p##4,p##5,p##6,p##7, \
                        p##8,p##9,p##10,p##11,p##12,p##13,p##14,p##15;
#define LOAD_SET(p, base) \
    p##0=(base)[0];  p##1=(base)[1];  p##2=(base)[2];  p##3=(base)[3];   \
    p##4=(base)[4];  p##5=(base)[5];  p##6=(base)[6];  p##7=(base)[7];   \
    p##8=(base)[8];  p##9=(base)[9];  p##10=(base)[10]; p##11=(base)[11];\
    p##12=(base)[12]; p##13=(base)[13]; p##14=(base)[14]; p##15=(base)[15];
#define DO_STEP(CDv, CDNv, J)                                         \
    RK4_STEP(CDv, CDNv)                                               \
    ob[2*(J)]   = P;                                                  \
    ob[2*(J)+1] = V;
#define STEPS_SET(p, NX)                                                     \
    DO_STEP(p##0,p##1,0)   DO_STEP(p##1,p##2,1)   DO_STEP(p##2,p##3,2)       \
    DO_STEP(p##3,p##4,3)   DO_STEP(p##4,p##5,4)   DO_STEP(p##5,p##6,5)       \
    DO_STEP(p##6,p##7,6)   DO_STEP(p##7,p##8,7)   DO_STEP(p##8,p##9,8)       \
    DO_STEP(p##9,p##10,9)  DO_STEP(p##10,p##11,10) DO_STEP(p##11,p##12,11)   \
    DO_STEP(p##12,p##13,12) DO_STEP(p##13,p##14,13) DO_STEP(p##14,p##15,14)  \
    DO_STEP(p##15, NX, 15)

__global__ void __launch_bounds__(256, 1)
rk4_chain_kernel(const float* __restrict__ u, const v2f* __restrict__ cdp,
                 const float* __restrict__ pk1, const float* __restrict__ pk2,
                 const float* __restrict__ pk3, const float* __restrict__ pk4,
                 const float* __restrict__ pk5, const float* __restrict__ pk6,
                 v2f* __restrict__ out2, int T)
{
    if (blockIdx.x != 0) {
        // ---- spinner (R3-proven): keep SCLK boosted until chain done ----
        const unsigned v0 = atomicAdd(&g_done_ctr, 0u);
        float a0 = (float)threadIdx.x + 1.0f, a1s = a0 + 0.5f, a2s = a0 + 1.5f,
              a3 = a0 + 2.5f, a4 = a0 + 3.5f, a5 = a0 + 4.5f, a6 = a0 + 5.5f,
              a7 = a0 + 6.5f;
        const float mu = 1.0000001f, ad = 0.4999999f;
        for (long it = 0; it < 20000000L; ++it) {
            a0 = __builtin_fmaf(a0, mu, ad); a1s = __builtin_fmaf(a1s, mu, ad);
            a2s = __builtin_fmaf(a2s, mu, ad); a3 = __builtin_fmaf(a3, mu, ad);
            a4 = __builtin_fmaf(a4, mu, ad); a5 = __builtin_fmaf(a5, mu, ad);
            a6 = __builtin_fmaf(a6, mu, ad); a7 = __builtin_fmaf(a7, mu, ad);
            if ((it & 1023) == 0) {
                if (atomicAdd(&g_done_ctr, 0u) != v0) break;
            }
        }
        asm volatile("" :: "v"(a0), "v"(a1s), "v"(a2s), "v"(a3),
                           "v"(a4), "v"(a5), "v"(a6), "v"(a7));
        return;
    }
    if (threadIdx.x != 0) return;

    const float k1 = *pk1, k2 = *pk2, k3 = *pk3;
    const float k4 = *pk4, k5 = *pk5, k6 = *pk6;

    const float c034 = 0.5f * k3 * k4;
    const float k36  = k3 * k6;
    const float k6u  = k6 * 1.0f;
    const float H2   = 0.05f;
    const float Hf   = 0.1f;
    const float H6   = 0.1f / 6.0f;
    const float H3   = 0.1f / 3.0f;

    const v2f CAc = { k1,        k5        };
    const v2f CBc = { k2,        k36       };
    const v2f CCc = { c034,     -k36       };
    const v2f cH2 = { k1 * H2,   k5 * H2   };   // CA*H/2
    const v2f cHc = { k1 * Hf,   k5 * Hf   };   // CA*H
    const v2f H2c = { H2,        H2        };
    const v2f Hc  = { Hf,        Hf        };
    const v2f H2q = { H2 * H2,   H2 * H2   };   // (H/2)^2
    const v2f HH2 = { Hf * H2,   Hf * H2   };   // H*H/2
    const v2f H6c = { H6,        H6        };
    const v2f H3c = { H3,        H3        };
    const v2f Hq6 = { Hf * Hf / 6.0f, Hf * Hf / 6.0f };  // H^2/6

    v2f P = { 0.f, 0.f };   // (x0, x1)
    v2f V = { 0.f, 0.f };   // (x2, x3)

    v2f* ob = out2;
    const int nb = T >> 4;           // 16-step blocks
    int b = 0;

    if (cdp != nullptr) {
        if (nb >= 1) {
            DECL_SET(A) DECL_SET(B)
            LOAD_SET(A, cdp)
            // software-pipeline init: a1 = CB*P + CD0, m1 = (x1^2, x0*x1)
            v2f a1, m1;
            a1.x = __builtin_fmaf(k2,  P.x, A0.x);
            a1.y = __builtin_fmaf(k36, P.y, A0.y);
            m1.x = P.y * P.y;
            m1.y = P.x * P.y;
            for (; b + 1 < nb; b += 2) {
                const v2f* nB = cdp + (size_t)(b + 1) * 16;
                LOAD_SET(B, nB)
                STEPS_SET(A, B0)
                ob += 32;
                const v2f* nA = cdp + (size_t)((b + 2 < nb) ? b + 2 : nb - 1) * 16;
                LOAD_SET(A, nA)
                STEPS_SET(B, A0)
                ob += 32;
            }
            if (b < nb) {            // odd nb: last block (CDN dummy on step 15)
                STEPS_SET(A, A15)
                ob += 32;
                ++b;
            }
        }
    } else {
        // -------- fallback (tiny d_ws): compute CDs inline --------
        v2f a1, m1;
        bool init = false;
        for (; b < nb; ++b) {
            const float* ub = u + (size_t)b * 16;
            DECL_SET(A)
            A0.x=k4*ub[0];  A0.y=k6u;  A1.x=k4*ub[1];  A1.y=k6u;
            A2.x=k4*ub[2];  A2.y=k6u;  A3.x=k4*ub[3];  A3.y=k6u;
            A4.x=k4*ub[4];  A4.y=k6u;  A5.x=k4*ub[5];  A5.y=k6u;
            A6.x=k4*ub[6];  A6.y=k6u;  A7.x=k4*ub[7];  A7.y=k6u;
            A8.x=k4*ub[8];  A8.y=k6u;  A9.x=k4*ub[9];  A9.y=k6u;
            A10.x=k4*ub[10]; A10.y=k6u; A11.x=k4*ub[11]; A11.y=k6u;
            A12.x=k4*ub[12]; A12.y=k6u; A13.x=k4*ub[13]; A13.y=k6u;
            A14.x=k4*ub[14]; A14.y=k6u; A15.x=k4*ub[15]; A15.y=k6u;
            if (!init) {
                a1.x = __builtin_fmaf(k2,  P.x, A0.x);
                a1.y = __builtin_fmaf(k36, P.y, A0.y);
                m1.x = P.y * P.y;
                m1.y = P.x * P.y;
                init = true;
            }
            v2f NX;
            if (b + 1 < nb) { NX.x = k4 * ub[16]; NX.y = k6u; }
            else            { NX = A15; }
            STEPS_SET(A, NX)
            ob += 32;
        }
    }

    // scalar tail (T % 16 != 0; not hit for T=200000)
    for (int t = nb << 4; t < T; ++t) {
        v2f cdv; cdv.x = k4 * u[t]; cdv.y = k6u;
        v2f a1, m1;
        a1.x = __builtin_fmaf(k2,  P.x, cdv.x);
        a1.y = __builtin_fmaf(k36, P.y, cdv.y);
        m1.x = P.y * P.y;
        m1.y = P.x * P.y;
        RK4_STEP(cdv, cdv)
        out2[2 * t]     = P;
        out2[2 * t + 1] = V;
    }

    __threadfence();
    atomicAdd(&g_done_ctr, 1u);
}

extern "C" void kernel_launch(void* const* d_in, const int* in_sizes, int n_in,
                              void* d_out, int out_size, void* d_ws, size_t ws_size,
                              hipStream_t stream)
{
    const float* u   = (const float*)d_in[0];
    const float* pk1 = (const float*)d_in[1];
    const float* pk2 = (const float*)d_in[2];
    const float* pk3 = (const float*)d_in[3];
    const float* pk4 = (const float*)d_in[4];
    const float* pk5 = (const float*)d_in[5];
    const float* pk6 = (const float*)d_in[6];
    v2f* out2 = (v2f*)d_out;
    const int T = in_sizes[0];

    v2f* cd = nullptr;
    if (ws_size >= (size_t)T * sizeof(v2f)) {
        cd = (v2f*)d_ws;
        const int pre_blocks = (T + 255) / 256;
        hipLaunchKernelGGL(cd_precompute_kernel, dim3(pre_blocks), dim3(256),
                           0, stream, u, pk4, pk6, cd, T);
    }

    hipLaunchKernelGGL(rk4_chain_kernel, dim3(256), dim3(256), 0, stream,
                       u, cd, pk1, pk2, pk3, pk4, pk5, pk6, out2, T);
}